// Round 4
// baseline (856.015 us; speedup 1.0000x reference)
//
#include <hip/hip_runtime.h>
#include <hip/hip_bf16.h>

// TemporalSpikeCoder latency encoding:
//   spike_times[b,f] = (int)((1 - x[b,f]) * 100)
//   out[b,t,f] = (spike_times[b,f] == t) ? 1.0f : 0.0f
// x [B=2048, F=1024] f32 (8.4 MB), out [B, T=100, F] f32 (839 MB).
//
// Write-BW-bound. R2 showed the block-local strided write pattern ran the
// output stream at only ~3 TB/s (DRAM row thrash: 8192 live waves writing
// 1 KiB chunks scattered over 839 MB). This version grid-strides LINEARLY
// over the output — at any instant the whole grid writes one dense ~8 MB
// window, same structure as the 6.2 TB/s fill kernel. x is re-read per t
// from L2 (8.4 MB, resident); nontemporal stores keep the output stream
// from evicting it.

constexpr int F  = 1024;
constexpr int T  = 100;
constexpr int F4 = F / 4;      // 256 float4s per feature row

typedef float v4f __attribute__((ext_vector_type(4)));

__global__ __launch_bounds__(256) void TemporalSpikeCoder_78125455114738_kernel(
    const float* __restrict__ x, float* __restrict__ out, int total4) {
    const int gsz = gridDim.x * blockDim.x;
    const v4f* __restrict__ x4 = reinterpret_cast<const v4f*>(x);
    v4f* __restrict__ o4 = reinterpret_cast<v4f*>(out);

    for (int i = blockIdx.x * blockDim.x + threadIdx.x; i < total4; i += gsz) {
        const unsigned f4 = (unsigned)i & (F4 - 1);   // feature float4 index
        const unsigned bt = (unsigned)i >> 8;         // b*T + t
        const unsigned b  = bt / T;                   // magic-mul div
        const int      t  = (int)(bt - b * T);

        const v4f xv = x4[b * F4 + f4];               // L2-hit after first touch
        // Match JAX: f32 math, truncation on int32 cast.
        v4f v;
        v.x = ((int)((1.0f - xv.x) * 100.0f) == t) ? 1.0f : 0.0f;
        v.y = ((int)((1.0f - xv.y) * 100.0f) == t) ? 1.0f : 0.0f;
        v.z = ((int)((1.0f - xv.z) * 100.0f) == t) ? 1.0f : 0.0f;
        v.w = ((int)((1.0f - xv.w) * 100.0f) == t) ? 1.0f : 0.0f;

        __builtin_nontemporal_store(v, &o4[i]);       // dense linear stream
    }
}

extern "C" void kernel_launch(void* const* d_in, const int* in_sizes, int n_in,
                              void* d_out, int out_size, void* d_ws, size_t ws_size,
                              hipStream_t stream) {
    const float* x = (const float*)d_in[0];
    float* out = (float*)d_out;
    const int total4 = out_size / 4;                  // 52,428,800 float4 stores
    const int block = 256;
    const int grid = 2048;                            // 8 blocks/CU, grid-stride
    TemporalSpikeCoder_78125455114738_kernel<<<grid, block, 0, stream>>>(x, out, total4);
}